// Round 10
// baseline (17.534 us; speedup 1.0000x reference)
//
#include <hip/hip_runtime.h>
#include <math.h>

#define AA 36
#define FWW 106
#define NTOT 122112        /* 32*106*36 */
#define BB 4
#define GG 64
#define STRIDE_PX 16

constexpr int BLOCK = 512;                               // 8 waves
constexpr int NW    = BLOCK / 64;                        // 8
constexpr int NBLK  = (NTOT + BLOCK - 1) / BLOCK;        // 239 (ragged tail; b folded in)

__device__ __forceinline__ float smooth_l1(float x) {
    float ax = fabsf(x);
    return (ax < 1.0f) ? 0.5f * ax * ax : ax - 0.5f;
}
__device__ __forceinline__ float frcp(float x) { return __builtin_amdgcn_rcpf(x); }

__global__ __launch_bounds__(BLOCK) void rpn_loss_main(
    const float* __restrict__ cls,
    const float* __restrict__ bbox2d,
    const float* __restrict__ bbox3d,
    const float* __restrict__ anchors,
    const float* __restrict__ means,
    const float* __restrict__ stds,
    const float* __restrict__ gt_boxes,
    const float* __restrict__ gt3d,
    const int*   __restrict__ gt_labels,
    float4* __restrict__ part)
{
    __shared__ float4 s_gt4[BB][GG];        // per-b compacted {gx1, gy1, gx2+1, gy2+1}
    __shared__ float  s_gS[BB][GG];         // per-b compacted area_g
    __shared__ int    s_gidx[BB][GG];       // compacted -> original g
    __shared__ int    s_K[BB];
    __shared__ float4 s_anch4[AA];          // {ax1, ay1, aw, ah}
    __shared__ float  s_anch[AA * 13];      // raw 9 fields (stride 13)
    __shared__ unsigned long long s_bal[NW];
    __shared__ float4 s_red[NW];

    const int tid  = threadIdx.x;
    const int lane = tid & 63;
    const int wv   = tid >> 6;
    const int n0   = blockIdx.x * BLOCK;
    const int n    = n0 + tid;
    const bool valid = (n < NTOT);

    const float4* __restrict__ gtb4 = reinterpret_cast<const float4*>(gt_boxes);

    // ---- prefetch all 4 cls rows up front (4 independent VMEM streams) ----
    float4 c[BB];
    #pragma unroll
    for (int bb = 0; bb < BB; ++bb) {
        c[bb] = make_float4(0.f, 0.f, 0.f, 0.f);
        if (valid) c[bb] = reinterpret_cast<const float4*>(cls)[(size_t)bb * NTOT + n];
    }

    // ---- stage anchors (threads 0..35, concurrent with prune) ----
    if (tid < AA) {
        float a[9];
        #pragma unroll
        for (int k = 0; k < 9; ++k) a[k] = anchors[tid * 9 + k];
        #pragma unroll
        for (int k = 0; k < 9; ++k) s_anch[tid * 13 + k] = a[k];
        s_anch4[tid] = make_float4(a[0], a[1], a[2] - a[0] + 1.0f, a[3] - a[1] + 1.0f);
    }

    // ---- block window(s): <=2 single-row x-spans (512 threads span <15 shifts) ----
    const int nlast = (n0 + BLOCK - 1 < NTOT) ? (n0 + BLOCK - 1) : (NTOT - 1);
    const int s0  = n0 / AA,  s1  = nlast / AA;
    const int sy0 = s0 / FWW, sy1 = s1 / FWW;
    float fxA0, fxA1, fyA, fxB0, fxB1, fyB;
    if (sy0 == sy1) {
        fxA0 = (float)((s0 % FWW) * STRIDE_PX); fxA1 = (float)((s1 % FWW) * STRIDE_PX);
        fyA  = (float)(sy0 * STRIDE_PX);
        fxB0 = fxA0; fxB1 = fxA1; fyB = fyA;
    } else {
        fxA0 = (float)((s0 % FWW) * STRIDE_PX); fxA1 = (float)((FWW - 1) * STRIDE_PX);
        fyA  = (float)(sy0 * STRIDE_PX);
        fxB0 = 0.0f;                            fxB1 = (float)((s1 % FWW) * STRIDE_PX);
        fyB  = (float)(sy1 * STRIDE_PX);
    }

    // ======== prune: wave wv tests batch (wv>>1), anchors {parity, parity+2, ...} ========
    {
        const int b_p    = wv >> 1;                 // wave-uniform
        const int parity = wv & 1;
        const float4 gt   = gtb4[b_p * GG + lane];  // this lane's GT for its batch
        const float  gz1p = gt.z + 1.0f;
        const float  gw1p = gt.w + 1.0f;
        const float  ag   = (gz1p - gt.x) * (gw1p - gt.y);

        bool pass = false;
        for (int a = parity; a < AA; a += 2) {      // wave-uniform a -> scalar loads
            const float ax1 = anchors[a * 9 + 0];
            const float ay1 = anchors[a * 9 + 1];
            const float aw  = anchors[a * 9 + 2] - ax1 + 1.0f;
            const float ah  = anchors[a * 9 + 3] - ay1 + 1.0f;
            const float thr = aw * ah + ag;
            float iwA = fminf(fxA1 + ax1 + aw, gz1p) - fmaxf(fxA0 + ax1, gt.x);
            float ihA = fminf(fyA  + ay1 + ah, gw1p) - fmaxf(fyA  + ay1, gt.y);
            iwA = fmaxf(fminf(iwA, aw), 0.0f);
            ihA = fmaxf(fminf(ihA, ah), 0.0f);
            pass |= (3.0f * iwA * ihA >= thr);
            float iwB = fminf(fxB1 + ax1 + aw, gz1p) - fmaxf(fxB0 + ax1, gt.x);
            float ihB = fminf(fyB  + ay1 + ah, gw1p) - fmaxf(fyB  + ay1, gt.y);
            iwB = fmaxf(fminf(iwB, aw), 0.0f);
            ihB = fmaxf(fminf(ihB, ah), 0.0f);
            pass |= (3.0f * iwB * ihB >= thr);
        }
        const unsigned long long wmask = __ballot(pass);
        if (lane == 0) s_bal[wv] = wmask;
    }
    __syncthreads();                                   // B1

    // ---- waves 0..3: combine ballots + stable compaction for batch wv ----
    if (wv < BB) {
        const unsigned long long mask = s_bal[2 * wv] | s_bal[2 * wv + 1];
        const float4 gt   = gtb4[wv * GG + lane];      // L2-warm re-read
        const float  gz1p = gt.z + 1.0f;
        const float  gw1p = gt.w + 1.0f;
        if ((mask >> lane) & 1ull) {
            const int pos = __popcll(mask & ((1ull << lane) - 1ull));
            s_gt4[wv][pos]  = make_float4(gt.x, gt.y, gz1p, gw1p);
            s_gS[wv][pos]   = (gz1p - gt.x) * (gw1p - gt.y);
            s_gidx[wv][pos] = lane;
        }
        if (lane == 0) s_K[wv] = __popcll(mask);
    }
    __syncthreads();                                   // B2

    // ================= per-thread ROI (once, shared by all 4 batches) =================
    const int aidx  = n % AA;
    const int shift = n / AA;
    const float sx  = (float)((shift % FWW) * STRIDE_PX);
    const float sy  = (float)((shift / FWW) * STRIDE_PX);
    const float4 A4 = s_anch4[aidx];
    const float aw  = A4.z;
    const float ah  = A4.w;
    const float x1  = sx + A4.x;
    const float y1  = sy + A4.y;
    const float x2p = x1 + aw;
    const float y2p = y1 + ah;
    const float ar  = aw * ah;

    float ce_s = 0.0f, l23 = 0.0f, nfg = 0.0f;

    #pragma unroll
    for (int bb = 0; bb < BB; ++bb) {
        const float lse = __logf(__expf(c[bb].x) + __expf(c[bb].y) +
                                 __expf(c[bb].z) + __expf(c[bb].w));
        const int K = s_K[bb];
        float bi = 0.0f, bS = 1.0f;
        int   bk = 0;
        if (valid) {
            #pragma unroll 2
            for (int k = 0; k < K; ++k) {
                const float4 g4 = s_gt4[bb][k];        // uniform-addr broadcast
                const float  Sg = s_gS[bb][k];
                const float iw = fminf(x2p, g4.z) - fmaxf(x1, g4.x);
                const float ih = fmaxf(fminf(y2p, g4.w) - fmaxf(y1, g4.y), 0.0f);
                const float inter = iw * ih;            // <=0 can never win (bi>=0)
                const float S     = ar + Sg;
                const bool upd = inter * bS > bi * S;   // exact first-max
                bi = upd ? inter : bi;
                bS = upd ? S     : bS;
                bk = upd ? k     : bk;
            }
        }
        const bool fg = valid && (3.0f * bi >= bS);     // exact: best_iou >= 0.5

        int label = 0;
        if (fg) label = gt_labels[bb * GG + s_gidx[bb][bk]];
        const float csel = (label == 0) ? c[bb].x : (label == 1) ? c[bb].y :
                           (label == 2) ? c[bb].z : c[bb].w;
        ce_s += valid ? (lse - csel) : 0.0f;

        if (fg) {
            nfg += 1.0f;
            const int   bg  = s_gidx[bb][bk];
            const float cx  = x1 + 0.5f * aw;
            const float cy  = y1 + 0.5f * ah;
            const float rw  = frcp(aw);
            const float rh  = frcp(ah);
            const float4 gq = s_gt4[bb][bk];            // {gx1, gy1, gx2+1, gy2+1}
            const float gw_ = gq.z - gq.x;
            const float gh_ = gq.w - gq.y;
            const float gcx = gq.x + 0.5f * gw_;
            const float gcy = gq.y + 0.5f * gh_;
            const size_t row = (size_t)bb * NTOT + n;
            float t2[4];
            t2[0] = (gcx - cx) * rw;
            t2[1] = (gcy - cy) * rh;
            t2[2] = __logf(gw_ * rw);
            t2[3] = __logf(gh_ * rh);
            const float4 p2 = reinterpret_cast<const float4*>(bbox2d)[row];
            const float p2a[4] = {p2.x, p2.y, p2.z, p2.w};
            #pragma unroll
            for (int k = 0; k < 4; ++k)
                l23 += smooth_l1(p2a[k] - (t2[k] - means[k]) * frcp(stds[k]));

            const float* an = &s_anch[aidx * 13];
            const float* g3 = gt3d + ((size_t)bb * GG + bg) * 7;
            float t3[7];
            t3[0] = (g3[0] - cx) * rw;
            t3[1] = (g3[1] - cy) * rh;
            t3[2] = g3[2] - an[4];
            t3[3] = __logf(g3[3] * frcp(an[5]));
            t3[4] = __logf(g3[4] * frcp(an[6]));
            t3[5] = __logf(g3[5] * frcp(an[7]));
            t3[6] = g3[6] - an[8];
            const float* p3 = bbox3d + row * 7;
            #pragma unroll
            for (int k = 0; k < 7; ++k)
                l23 += smooth_l1(p3[k] - (t3[k] - means[4 + k]) * frcp(stds[4 + k]));
        }
    }

    // ===== reduction: {ce, l23, nfg} wave butterflies -> 8 partials -> 1 =====
    #pragma unroll
    for (int off = 32; off > 0; off >>= 1) {
        ce_s += __shfl_down(ce_s, off, 64);
        l23  += __shfl_down(l23,  off, 64);
        nfg  += __shfl_down(nfg,  off, 64);
    }
    if (lane == 0) s_red[wv] = make_float4(ce_s, l23, nfg, 0.f);
    __syncthreads();                                   // B3
    if (tid < NW) {
        float4 p = s_red[tid];
        #pragma unroll
        for (int m = 1; m < NW; m <<= 1) {
            p.x += __shfl_xor(p.x, m, 64);
            p.y += __shfl_xor(p.y, m, 64);
            p.z += __shfl_xor(p.z, m, 64);
        }
        if (tid == 0) part[blockIdx.x] = p;
    }
}

__global__ __launch_bounds__(256) void rpn_loss_fin(
    const float4* __restrict__ part, float* __restrict__ out)
{
    __shared__ float4 sh[4];
    float4 s = make_float4(0.f, 0.f, 0.f, 0.f);
    for (int i = threadIdx.x; i < NBLK; i += 256) {
        const float4 p = part[i];
        s.x += p.x; s.y += p.y; s.z += p.z;
    }
    #pragma unroll
    for (int off = 32; off > 0; off >>= 1) {
        s.x += __shfl_down(s.x, off, 64);
        s.y += __shfl_down(s.y, off, 64);
        s.z += __shfl_down(s.z, off, 64);
    }
    const int lane = threadIdx.x & 63;
    const int wv   = threadIdx.x >> 6;
    if (lane == 0) sh[wv] = s;
    __syncthreads();
    if (threadIdx.x == 0) {
        float ce = 0.f, l23 = 0.f, nfg = 0.f;
        #pragma unroll
        for (int i = 0; i < 4; ++i) {
            ce += sh[i].x; l23 += sh[i].y; nfg += sh[i].z;
        }
        out[0] = ce / (float)((size_t)BB * NTOT) + l23 / fmaxf(nfg, 1.0f);
    }
}

extern "C" void kernel_launch(void* const* d_in, const int* in_sizes, int n_in,
                              void* d_out, int out_size, void* d_ws, size_t ws_size,
                              hipStream_t stream) {
    const float* cls     = (const float*)d_in[0];
    // d_in[1] = prob (unused by the loss)
    const float* bbox2d  = (const float*)d_in[2];
    const float* bbox3d  = (const float*)d_in[3];
    // d_in[4] = rois — reconstructed from anchors + linear index
    const float* anchors = (const float*)d_in[5];
    const float* means   = (const float*)d_in[6];
    const float* stds    = (const float*)d_in[7];
    const float* gtb     = (const float*)d_in[8];
    const float* gt3     = (const float*)d_in[9];
    const int*   glbl    = (const int*)d_in[10];
    float4* part = (float4*)d_ws;      // NBLK float4 partials, fully overwritten
    float*  out  = (float*)d_out;

    rpn_loss_main<<<dim3(NBLK), BLOCK, 0, stream>>>(cls, bbox2d, bbox3d, anchors,
                                                    means, stds, gtb, gt3, glbl, part);
    rpn_loss_fin<<<1, 256, 0, stream>>>(part, out);
}

// Round 12
// 16.065 us; speedup vs baseline: 1.0914x; 1.0914x over previous
//
#include <hip/hip_runtime.h>
#include <hip/hip_cooperative_groups.h>
#include <math.h>

#define AA 36
#define FWW 106
#define NTOT 122112        /* 32*106*36 */
#define BB 4
#define GG 64
#define STRIDE_PX 16

constexpr int BLOCK = 512;                               // 8 waves
constexpr int NW    = BLOCK / 64;                        // 8
constexpr int BLOCKS_PER_B = (NTOT + BLOCK - 1) / BLOCK; // 239 (last block ragged)
constexpr int NBLK = BB * BLOCKS_PER_B;                  // 956 virtual blocks
constexpr int GRID = 512;                                // persistent grid (2 blocks/CU)
constexpr int NCU  = 256;

__device__ __forceinline__ float smooth_l1(float x) {
    float ax = fabsf(x);
    return (ax < 1.0f) ? 0.5f * ax * ax : ax - 0.5f;
}
__device__ __forceinline__ float frcp(float x) { return __builtin_amdgcn_rcpf(x); }

// ---- shared-state bundle lives in the kernels; body is shared ----
__device__ __forceinline__ void process_vblock(
    const int vb, const int tid, const int lane, const int wv, const int wvu,
    const float* __restrict__ cls, const float* __restrict__ bbox2d,
    const float* __restrict__ bbox3d, const float* __restrict__ anchors,
    const float* __restrict__ means, const float* __restrict__ stds,
    const float* __restrict__ gt_boxes, const float* __restrict__ gt3d,
    const int* __restrict__ gt_labels,
    const float4* s_anch4, const float* s_anch,
    float4* s_gt4, float* s_gS, int* s_gidx,
    unsigned long long* s_bal, float4* s_red, int* s_K,
    float4* __restrict__ part)
{
    const int b    = vb / BLOCKS_PER_B;            // block-uniform
    const int bpos = vb % BLOCKS_PER_B;
    const int n0   = bpos * BLOCK;
    const int n    = n0 + tid;
    const bool valid = (n < NTOT);

    const float4* __restrict__ gtb = reinterpret_cast<const float4*>(gt_boxes) + b * GG;

    // ---- early: own cls row ----
    const size_t row = (size_t)b * NTOT + n;
    float4 c = make_float4(0.f, 0.f, 0.f, 0.f);
    if (valid) c = reinterpret_cast<const float4*>(cls)[row];

    // ---- block window(s): <=2 single-row x-spans ----
    const int nlast = (n0 + BLOCK - 1 < NTOT) ? (n0 + BLOCK - 1) : (NTOT - 1);
    const int s0  = n0 / AA,  s1  = nlast / AA;
    const int sy0 = s0 / FWW, sy1 = s1 / FWW;
    float fxA0, fxA1, fyA, fxB0, fxB1, fyB;
    if (sy0 == sy1) {
        fxA0 = (float)((s0 % FWW) * STRIDE_PX); fxA1 = (float)((s1 % FWW) * STRIDE_PX);
        fyA  = (float)(sy0 * STRIDE_PX);
        fxB0 = fxA0; fxB1 = fxA1; fyB = fyA;
    } else {
        fxA0 = (float)((s0 % FWW) * STRIDE_PX); fxA1 = (float)((FWW - 1) * STRIDE_PX);
        fyA  = (float)(sy0 * STRIDE_PX);
        fxB0 = 0.0f;                            fxB1 = (float)((s1 % FWW) * STRIDE_PX);
        fyB  = (float)(sy1 * STRIDE_PX);
    }

    // this lane's GT (4 KB, L2-warm)
    const float4 gt   = gtb[lane];
    const float  gz1p = gt.z + 1.0f;
    const float  gw1p = gt.w + 1.0f;
    const float  ag   = (gz1p - gt.x) * (gw1p - gt.y);

    // ---- parallel fg-feasibility prune: wave wv tests anchors {wvu, wvu+8, ...} ----
    bool pass = false;
    for (int a = wvu; a < AA; a += NW) {      // wave-uniform a -> scalar loads
        const float ax1 = anchors[a * 9 + 0];
        const float ay1 = anchors[a * 9 + 1];
        const float aw  = anchors[a * 9 + 2] - ax1 + 1.0f;
        const float ah  = anchors[a * 9 + 3] - ay1 + 1.0f;
        const float thr = aw * ah + ag;
        float iwA = fminf(fxA1 + ax1 + aw, gz1p) - fmaxf(fxA0 + ax1, gt.x);
        float ihA = fminf(fyA  + ay1 + ah, gw1p) - fmaxf(fyA  + ay1, gt.y);
        iwA = fmaxf(fminf(iwA, aw), 0.0f);
        ihA = fmaxf(fminf(ihA, ah), 0.0f);
        pass |= (3.0f * iwA * ihA >= thr);
        float iwB = fminf(fxB1 + ax1 + aw, gz1p) - fmaxf(fxB0 + ax1, gt.x);
        float ihB = fminf(fyB  + ay1 + ah, gw1p) - fmaxf(fyB  + ay1, gt.y);
        iwB = fmaxf(fminf(iwB, aw), 0.0f);
        ihB = fmaxf(fminf(ihB, ah), 0.0f);
        pass |= (3.0f * iwB * ihB >= thr);
    }
    const unsigned long long wmask = __ballot(pass);
    if (lane == 0) s_bal[wv] = wmask;
    __syncthreads();                                   // B1

    // ---- wave 0: OR ballots, stable compaction ----
    if (wv == 0) {
        unsigned long long mask = 0ull;
        #pragma unroll
        for (int j = 0; j < NW; ++j) mask |= s_bal[j];
        if ((mask >> lane) & 1ull) {
            const int pos = __popcll(mask & ((1ull << lane) - 1ull));
            s_gt4[pos]  = make_float4(gt.x, gt.y, gz1p, gw1p);
            s_gS[pos]   = ag;
            s_gidx[pos] = lane;
        }
        if (lane == 0) *s_K = __popcll(mask);
    }
    __syncthreads();                                   // B2

    // ---- per-thread ROI + argmax ----
    const int aidx  = n % AA;
    const int shift = n / AA;
    const float sx  = (float)((shift % FWW) * STRIDE_PX);
    const float sy  = (float)((shift / FWW) * STRIDE_PX);
    const float4 A4 = s_anch4[aidx];
    const float aw  = A4.z;
    const float ah  = A4.w;
    const float x1  = sx + A4.x;
    const float y1  = sy + A4.y;
    const float x2p = x1 + aw;
    const float y2p = y1 + ah;
    const float ar  = aw * ah;

    const float lse = __logf(__expf(c.x) + __expf(c.y) + __expf(c.z) + __expf(c.w));

    const int K = *s_K;
    float bi = 0.0f, bS = 1.0f;
    int   bk = 0;
    if (valid) {
        #pragma unroll 2
        for (int k = 0; k < K; ++k) {
            const float4 g4 = s_gt4[k];        // uniform-addr broadcast
            const float  Sg = s_gS[k];
            const float iw = fminf(x2p, g4.z) - fmaxf(x1, g4.x);
            const float ih = fmaxf(fminf(y2p, g4.w) - fmaxf(y1, g4.y), 0.0f);
            const float inter = iw * ih;            // <=0 can never win (bi>=0)
            const float S     = ar + Sg;
            const bool upd = inter * bS > bi * S;   // exact first-max
            bi = upd ? inter : bi;
            bS = upd ? S     : bS;
            bk = upd ? k     : bk;
        }
    }
    const bool fg = valid && (3.0f * bi >= bS);   // exact: best_iou >= 0.5

    int label = 0;
    if (fg) label = gt_labels[b * GG + s_gidx[bk]];
    const float csel = (label == 0) ? c.x : (label == 1) ? c.y :
                       (label == 2) ? c.z : c.w;
    const float ce = valid ? (lse - csel) : 0.0f;

    // ---- bbox losses (fg only; rare) ----
    float l23 = 0.0f;
    if (fg) {
        const int   bg  = s_gidx[bk];
        const float cx  = x1 + 0.5f * aw;
        const float cy  = y1 + 0.5f * ah;
        const float rw  = frcp(aw);
        const float rh  = frcp(ah);
        const float4 gq = s_gt4[bk];            // {gx1, gy1, gx2+1, gy2+1}
        const float gw_ = gq.z - gq.x;
        const float gh_ = gq.w - gq.y;
        const float gcx = gq.x + 0.5f * gw_;
        const float gcy = gq.y + 0.5f * gh_;
        float t2[4];
        t2[0] = (gcx - cx) * rw;
        t2[1] = (gcy - cy) * rh;
        t2[2] = __logf(gw_ * rw);
        t2[3] = __logf(gh_ * rh);
        const float4 p2 = reinterpret_cast<const float4*>(bbox2d)[row];
        const float p2a[4] = {p2.x, p2.y, p2.z, p2.w};
        #pragma unroll
        for (int k = 0; k < 4; ++k)
            l23 += smooth_l1(p2a[k] - (t2[k] - means[k]) * frcp(stds[k]));

        const float* an = &s_anch[aidx * 13];
        const float* g3 = gt3d + ((size_t)b * GG + bg) * 7;
        float t3[7];
        t3[0] = (g3[0] - cx) * rw;
        t3[1] = (g3[1] - cy) * rh;
        t3[2] = g3[2] - an[4];
        t3[3] = __logf(g3[3] * frcp(an[5]));
        t3[4] = __logf(g3[4] * frcp(an[6]));
        t3[5] = __logf(g3[5] * frcp(an[7]));
        t3[6] = g3[6] - an[8];
        const float* p3 = bbox3d + row * 7;
        #pragma unroll
        for (int k = 0; k < 7; ++k)
            l23 += smooth_l1(p3[k] - (t3[k] - means[4 + k]) * frcp(stds[4 + k]));
    }

    // ---- reduction: ce + l23 butterflies, nfg via ballot ----
    float vce = ce, vl = l23;
    #pragma unroll
    for (int off = 32; off > 0; off >>= 1) {
        vce += __shfl_down(vce, off, 64);
        vl  += __shfl_down(vl,  off, 64);
    }
    const float nfgw = (float)__popcll(__ballot(fg));
    if (lane == 0) s_red[wv] = make_float4(vce, vl, nfgw, 0.f);
    __syncthreads();                                   // B3
    if (tid < NW) {
        float4 p = s_red[tid];
        #pragma unroll
        for (int m = 1; m < NW; m <<= 1) {
            p.x += __shfl_xor(p.x, m, 64);
            p.y += __shfl_xor(p.y, m, 64);
            p.z += __shfl_xor(p.z, m, 64);
        }
        if (tid == 0) part[vb] = p;
    }
}

#define SHARED_DECLS                                                      \
    __shared__ float4 s_gt4[GG];                                          \
    __shared__ float  s_gS[GG];                                           \
    __shared__ int    s_gidx[GG];                                         \
    __shared__ float4 s_anch4[AA];                                        \
    __shared__ float  s_anch[AA * 13];                                    \
    __shared__ unsigned long long s_bal[NW];                              \
    __shared__ float4 s_red[NW];                                          \
    __shared__ int    s_K;

#define STAGE_ANCHORS                                                     \
    if (tid < AA) {                                                       \
        float a[9];                                                       \
        _Pragma("unroll")                                                 \
        for (int k = 0; k < 9; ++k) a[k] = anchors[tid * 9 + k];          \
        _Pragma("unroll")                                                 \
        for (int k = 0; k < 9; ++k) s_anch[tid * 13 + k] = a[k];          \
        s_anch4[tid] = make_float4(a[0], a[1], a[2] - a[0] + 1.0f,        \
                                   a[3] - a[1] + 1.0f);                   \
    }

// ================= persistent cooperative kernel =================
__global__ __launch_bounds__(BLOCK, 4) void rpn_loss_coop(
    const float* __restrict__ cls, const float* __restrict__ bbox2d,
    const float* __restrict__ bbox3d, const float* __restrict__ anchors,
    const float* __restrict__ means, const float* __restrict__ stds,
    const float* __restrict__ gt_boxes, const float* __restrict__ gt3d,
    const int* __restrict__ gt_labels,
    float4* __restrict__ part, float* __restrict__ out)
{
    SHARED_DECLS
    const int tid  = threadIdx.x;
    const int lane = tid & 63;
    const int wv   = tid >> 6;
    const int wvu  = __builtin_amdgcn_readfirstlane(wv);

    STAGE_ANCHORS

    for (int vb = blockIdx.x; vb < NBLK; vb += GRID)
        process_vblock(vb, tid, lane, wv, wvu, cls, bbox2d, bbox3d, anchors,
                       means, stds, gt_boxes, gt3d, gt_labels,
                       s_anch4, s_anch, s_gt4, s_gS, s_gidx, s_bal, s_red, &s_K,
                       part);

    __threadfence();
    cooperative_groups::this_grid().sync();

    if (blockIdx.x == 0) {
        float ce_t = 0.f, l_t = 0.f, nfg_t = 0.f;
        for (int i = tid; i < NBLK; i += BLOCK) {
            const float4 p = part[i];
            ce_t += p.x; l_t += p.y; nfg_t += p.z;
        }
        #pragma unroll
        for (int off = 32; off > 0; off >>= 1) {
            ce_t  += __shfl_down(ce_t,  off, 64);
            l_t   += __shfl_down(l_t,   off, 64);
            nfg_t += __shfl_down(nfg_t, off, 64);
        }
        __syncthreads();
        if (lane == 0) s_red[wv] = make_float4(ce_t, l_t, nfg_t, 0.f);
        __syncthreads();
        if (tid == 0) {
            float a = 0.f, bs = 0.f, g = 0.f;
            #pragma unroll
            for (int i = 0; i < NW; ++i) { a += s_red[i].x; bs += s_red[i].y; g += s_red[i].z; }
            out[0] = a / (float)((size_t)BB * NTOT) + bs / fmaxf(g, 1.0f);
        }
    }
}

// ================= fallback: two-kernel path (R9 structure) =================
__global__ __launch_bounds__(BLOCK) void rpn_loss_main(
    const float* __restrict__ cls, const float* __restrict__ bbox2d,
    const float* __restrict__ bbox3d, const float* __restrict__ anchors,
    const float* __restrict__ means, const float* __restrict__ stds,
    const float* __restrict__ gt_boxes, const float* __restrict__ gt3d,
    const int* __restrict__ gt_labels, float4* __restrict__ part)
{
    SHARED_DECLS
    const int tid  = threadIdx.x;
    const int lane = tid & 63;
    const int wv   = tid >> 6;
    const int wvu  = __builtin_amdgcn_readfirstlane(wv);
    STAGE_ANCHORS
    process_vblock(blockIdx.x, tid, lane, wv, wvu, cls, bbox2d, bbox3d, anchors,
                   means, stds, gt_boxes, gt3d, gt_labels,
                   s_anch4, s_anch, s_gt4, s_gS, s_gidx, s_bal, s_red, &s_K, part);
}

__global__ __launch_bounds__(256) void rpn_loss_fin(
    const float4* __restrict__ part, float* __restrict__ out)
{
    __shared__ float4 sh[4];
    float4 s = make_float4(0.f, 0.f, 0.f, 0.f);
    for (int i = threadIdx.x; i < NBLK; i += 256) {
        const float4 p = part[i];
        s.x += p.x; s.y += p.y; s.z += p.z;
    }
    #pragma unroll
    for (int off = 32; off > 0; off >>= 1) {
        s.x += __shfl_down(s.x, off, 64);
        s.y += __shfl_down(s.y, off, 64);
        s.z += __shfl_down(s.z, off, 64);
    }
    const int lane = threadIdx.x & 63;
    const int wv   = threadIdx.x >> 6;
    if (lane == 0) sh[wv] = s;
    __syncthreads();
    if (threadIdx.x == 0) {
        float ce = 0.f, l23 = 0.f, nfg = 0.f;
        #pragma unroll
        for (int i = 0; i < 4; ++i) { ce += sh[i].x; l23 += sh[i].y; nfg += sh[i].z; }
        out[0] = ce / (float)((size_t)BB * NTOT) + l23 / fmaxf(nfg, 1.0f);
    }
}

extern "C" void kernel_launch(void* const* d_in, const int* in_sizes, int n_in,
                              void* d_out, int out_size, void* d_ws, size_t ws_size,
                              hipStream_t stream) {
    const float* cls     = (const float*)d_in[0];
    // d_in[1] = prob (unused by the loss)
    const float* bbox2d  = (const float*)d_in[2];
    const float* bbox3d  = (const float*)d_in[3];
    // d_in[4] = rois — reconstructed from anchors + linear index
    const float* anchors = (const float*)d_in[5];
    const float* means   = (const float*)d_in[6];
    const float* stds    = (const float*)d_in[7];
    const float* gtb     = (const float*)d_in[8];
    const float* gt3     = (const float*)d_in[9];
    const int*   glbl    = (const int*)d_in[10];
    float4* part = (float4*)d_ws;      // NBLK float4 partials, fully overwritten
    float*  out  = (float*)d_out;

    // deterministic, capture-safe co-residency check
    int maxActive = 0;
    hipError_t oe = hipOccupancyMaxActiveBlocksPerMultiprocessor(
        &maxActive, reinterpret_cast<const void*>(rpn_loss_coop), BLOCK, 0);
    const bool use_coop = (oe == hipSuccess) && (maxActive * NCU >= GRID);

    if (use_coop) {
        void* args[] = {
            (void*)&cls, (void*)&bbox2d, (void*)&bbox3d, (void*)&anchors,
            (void*)&means, (void*)&stds, (void*)&gtb, (void*)&gt3,
            (void*)&glbl, (void*)&part, (void*)&out
        };
        hipError_t le = hipLaunchCooperativeKernel(
            reinterpret_cast<void*>(rpn_loss_coop), dim3(GRID), dim3(BLOCK),
            args, 0, stream);
        if (le == hipSuccess) return;
        // fall through to two-kernel path if the coop launch was rejected
    }
    rpn_loss_main<<<dim3(NBLK), BLOCK, 0, stream>>>(cls, bbox2d, bbox3d, anchors,
                                                    means, stds, gtb, gt3, glbl, part);
    rpn_loss_fin<<<1, 256, 0, stream>>>(part, out);
}